// Round 5
// baseline (973.343 us; speedup 1.0000x reference)
//
#include <hip/hip_runtime.h>
#include <stdint.h>

// ---------------------------------------------------------------------------
// TransformerBlock: rmsnorm -> QKV -> RoPE -> causal flash attn -> +x ->
//                   rmsnorm -> swiglu FFN -> +O
// bf16 MFMA everywhere; Q/K path uses hi/lo bf16 split (3-pass MFMA) because
// softmax is near-one-hot on scores with sigma~900.
// R5: flash_k + split-gemm epilogue reverted VERBATIM to the R0-verified
// variant (308 us, absmax 32). The R3/R4 S^T rework failed with build-
// dependent absmax (~2000) - shelved pending disasm. New this round:
// gemm_ffn13_k fuses w1-GEMM + w3-GEMM + swiglu into one kernel (A staged
// once, dual accumulators, silu epilogue) killing the 200+ MB intermediate.
// ---------------------------------------------------------------------------

typedef short bf16x8 __attribute__((ext_vector_type(8)));
typedef float f32x4  __attribute__((ext_vector_type(4)));

#define DEV static __device__ __forceinline__

DEV float bf2f(uint32_t u) { uint32_t v = u << 16; float f; __builtin_memcpy(&f, &v, 4); return f; }
DEV uint16_t f2bf(float f) {
  uint32_t u; __builtin_memcpy(&u, &f, 4);
  u = (u + 0x7fffu + ((u >> 16) & 1u)) >> 16;   // RNE
  return (uint16_t)u;
}

DEV void gl_lds16(const uint16_t* g, uint16_t* l) {
  __builtin_amdgcn_global_load_lds((const __attribute__((address_space(1))) uint32_t*)g,
                                   (__attribute__((address_space(3))) uint32_t*)l, 16, 0, 0);
}

// ---------------------------- weight conversion ----------------------------

__global__ __launch_bounds__(256) void cvt_bf16_k(const float* __restrict__ src,
                                                  uint16_t* __restrict__ dst, int n4) {
  const int t = blockIdx.x * 256 + threadIdx.x;
  if (t >= n4) return;
  const float4 v = ((const float4*)src)[t];
  ushort4 o; o.x = f2bf(v.x); o.y = f2bf(v.y); o.z = f2bf(v.z); o.w = f2bf(v.w);
  ((ushort4*)dst)[t] = o;
}

__global__ __launch_bounds__(256) void cvt_split_qk_k(const float* __restrict__ qw,
                                                      const float* __restrict__ kw,
                                                      uint16_t* __restrict__ hi,
                                                      uint16_t* __restrict__ lo) {
  const int t = blockIdx.x * 256 + threadIdx.x;    // 2048*256 float4s
  const int row = t >> 8, c4 = t & 255;
  const float* src = (row < 1024) ? (qw + (size_t)row * 1024)
                                  : (kw + (size_t)(row - 1024) * 1024);
  const float4 v = ((const float4*)src)[c4];
  ushort4 h, l;
  h.x = f2bf(v.x); l.x = f2bf(v.x - bf2f(h.x));
  h.y = f2bf(v.y); l.y = f2bf(v.y - bf2f(h.y));
  h.z = f2bf(v.z); l.z = f2bf(v.z - bf2f(h.z));
  h.w = f2bf(v.w); l.w = f2bf(v.w - bf2f(h.w));
  ((ushort4*)hi)[t] = h; ((ushort4*)lo)[t] = l;
}

// -------------------------------- rmsnorm ----------------------------------

template <bool SPLIT>
__global__ __launch_bounds__(256) void rmsnorm_k(const float* __restrict__ xin,
                                                 const float* __restrict__ g,
                                                 uint16_t* __restrict__ hi,
                                                 uint16_t* __restrict__ lo) {
  const int row = blockIdx.x, t = threadIdx.x;
  const float4 v = ((const float4*)(xin + (size_t)row * 1024))[t];
  float ss = v.x * v.x + v.y * v.y + v.z * v.z + v.w * v.w;
#pragma unroll
  for (int m = 1; m < 64; m <<= 1) ss += __shfl_xor(ss, m);
  __shared__ float red[4];
  if ((t & 63) == 0) red[t >> 6] = ss;
  __syncthreads();
  const float rinv = rsqrtf((red[0] + red[1] + red[2] + red[3]) * (1.0f / 1024.0f) + 1e-5f);
  const float4 gv = ((const float4*)g)[t];
  float y[4] = { v.x * rinv * gv.x, v.y * rinv * gv.y, v.z * rinv * gv.z, v.w * rinv * gv.w };
  ushort4 h; h.x = f2bf(y[0]); h.y = f2bf(y[1]); h.z = f2bf(y[2]); h.w = f2bf(y[3]);
  ((ushort4*)(hi + (size_t)row * 1024))[t] = h;
  if constexpr (SPLIT) {
    ushort4 l;
    l.x = f2bf(y[0] - bf2f(h.x)); l.y = f2bf(y[1] - bf2f(h.y));
    l.z = f2bf(y[2] - bf2f(h.z)); l.w = f2bf(y[3] - bf2f(h.w));
    ((ushort4*)(lo + (size_t)row * 1024))[t] = l;
  }
}

// ------------------------ GEMM  C[M,N] = A[M,K] @ B[N,K]^T ------------------
// 128x128 tile, BK=64, 4 waves (2x2), 16x16x32 bf16 MFMA.
// LDS tiles XOR-swizzled: slot [r][g] holds global colgrp g^(r&7).

template <int OUT>   // 0: bf16 out; 1: f32 out + residual add
__global__ __launch_bounds__(256) void gemm_bt_k(const uint16_t* __restrict__ A,
                                                 const uint16_t* __restrict__ B,
                                                 void* __restrict__ C,
                                                 const float* __restrict__ resid,
                                                 int N, int K) {
  __shared__ __align__(16) uint16_t As[128 * 64];
  __shared__ __align__(16) uint16_t Bs[128 * 64];
  const int t = threadIdx.x, w = t >> 6, lane = t & 63, m16 = lane & 15, quad = lane >> 4;
  const int wm = (w >> 1) * 64, wn = (w & 1) * 64;
  const int mBase = blockIdx.y * 128, nBase = blockIdx.x * 128;
  f32x4 acc[4][4];
  const f32x4 vz = {0.f, 0.f, 0.f, 0.f};
#pragma unroll
  for (int i = 0; i < 4; ++i)
#pragma unroll
    for (int j = 0; j < 4; ++j) acc[i][j] = vz;
  const int r_ = t >> 3, g_ = t & 7, sg = g_ ^ (r_ & 7);   // (it*32) % 8 == 0
  const uint16_t* ag = A + (size_t)(mBase + r_) * K + sg * 8;
  const uint16_t* bg = B + (size_t)(nBase + r_) * K + sg * 8;
  for (int k0 = 0; k0 < K; k0 += 64) {
#pragma unroll
    for (int it = 0; it < 4; ++it) {
      gl_lds16(ag + (size_t)(it * 32) * K + k0, As + it * 2048 + t * 8);
      gl_lds16(bg + (size_t)(it * 32) * K + k0, Bs + it * 2048 + t * 8);
    }
    __syncthreads();
#pragma unroll
    for (int ks = 0; ks < 2; ++ks) {
      bf16x8 af[4], bf4[4];
      const int cg = ks * 4 + quad;
#pragma unroll
      for (int i = 0; i < 4; ++i) {
        const int rA = wm + i * 16 + m16;
        af[i] = *(const bf16x8*)(As + rA * 64 + ((cg ^ (rA & 7)) * 8));
        const int rB = wn + i * 16 + m16;
        bf4[i] = *(const bf16x8*)(Bs + rB * 64 + ((cg ^ (rB & 7)) * 8));
      }
#pragma unroll
      for (int i = 0; i < 4; ++i)
#pragma unroll
        for (int j = 0; j < 4; ++j)
          acc[i][j] = __builtin_amdgcn_mfma_f32_16x16x32_bf16(af[i], bf4[j], acc[i][j], 0, 0, 0);
    }
    __syncthreads();
  }
#pragma unroll
  for (int i = 0; i < 4; ++i) {
    const int row0 = mBase + wm + i * 16 + quad * 4;
#pragma unroll
    for (int j = 0; j < 4; ++j) {
      const int col = nBase + wn + j * 16 + m16;
#pragma unroll
      for (int r = 0; r < 4; ++r) {
        const size_t idx = (size_t)(row0 + r) * N + col;
        const float v = acc[i][j][r];
        if constexpr (OUT == 1) ((float*)C)[idx] = v + resid[idx];
        else                    ((uint16_t*)C)[idx] = f2bf(v);
      }
    }
  }
}

// --------------- fused FFN up-projection: silu(A@W1^T) * (A@W3^T) ----------
// A [8192][1024], W1/W3 [4096][1024], out bf16 [8192][4096]. A staged once,
// dual accumulators, swiglu in the epilogue (kills abuf/gbuf round-trip).

__global__ __launch_bounds__(256) void gemm_ffn13_k(const uint16_t* __restrict__ A,
                                                    const uint16_t* __restrict__ B1,
                                                    const uint16_t* __restrict__ B3,
                                                    uint16_t* __restrict__ C) {
  const int N = 4096, K = 1024;
  __shared__ __align__(16) uint16_t As[128 * 64];
  __shared__ __align__(16) uint16_t B1s[128 * 64];
  __shared__ __align__(16) uint16_t B3s[128 * 64];
  const int t = threadIdx.x, w = t >> 6, lane = t & 63, m16 = lane & 15, quad = lane >> 4;
  const int wm = (w >> 1) * 64, wn = (w & 1) * 64;
  const int mBase = blockIdx.y * 128, nBase = blockIdx.x * 128;
  f32x4 acc1[4][4], acc3[4][4];
  const f32x4 vz = {0.f, 0.f, 0.f, 0.f};
#pragma unroll
  for (int i = 0; i < 4; ++i)
#pragma unroll
    for (int j = 0; j < 4; ++j) { acc1[i][j] = vz; acc3[i][j] = vz; }
  const int r_ = t >> 3, g_ = t & 7, sg = g_ ^ (r_ & 7);
  const uint16_t* ag  = A  + (size_t)(mBase + r_) * K + sg * 8;
  const uint16_t* b1g = B1 + (size_t)(nBase + r_) * K + sg * 8;
  const uint16_t* b3g = B3 + (size_t)(nBase + r_) * K + sg * 8;
  for (int k0 = 0; k0 < K; k0 += 64) {
#pragma unroll
    for (int it = 0; it < 4; ++it) {
      gl_lds16(ag  + (size_t)(it * 32) * K + k0, As  + it * 2048 + t * 8);
      gl_lds16(b1g + (size_t)(it * 32) * K + k0, B1s + it * 2048 + t * 8);
      gl_lds16(b3g + (size_t)(it * 32) * K + k0, B3s + it * 2048 + t * 8);
    }
    __syncthreads();
#pragma unroll
    for (int ks = 0; ks < 2; ++ks) {
      bf16x8 af[4], b1f[4], b3f[4];
      const int cg = ks * 4 + quad;
#pragma unroll
      for (int i = 0; i < 4; ++i) {
        const int rA = wm + i * 16 + m16;
        af[i] = *(const bf16x8*)(As + rA * 64 + ((cg ^ (rA & 7)) * 8));
        const int rB = wn + i * 16 + m16;
        const int offB = rB * 64 + ((cg ^ (rB & 7)) * 8);
        b1f[i] = *(const bf16x8*)(B1s + offB);
        b3f[i] = *(const bf16x8*)(B3s + offB);
      }
#pragma unroll
      for (int i = 0; i < 4; ++i)
#pragma unroll
        for (int j = 0; j < 4; ++j) {
          acc1[i][j] = __builtin_amdgcn_mfma_f32_16x16x32_bf16(af[i], b1f[j], acc1[i][j], 0, 0, 0);
          acc3[i][j] = __builtin_amdgcn_mfma_f32_16x16x32_bf16(af[i], b3f[j], acc3[i][j], 0, 0, 0);
        }
    }
    __syncthreads();
  }
#pragma unroll
  for (int i = 0; i < 4; ++i) {
    const int row0 = mBase + wm + i * 16 + quad * 4;
#pragma unroll
    for (int j = 0; j < 4; ++j) {
      const int col = nBase + wn + j * 16 + m16;
#pragma unroll
      for (int r = 0; r < 4; ++r) {
        const float v1 = acc1[i][j][r];
        const float v3 = acc3[i][j][r];
        const float sw = v1 / (1.f + __expf(-v1));
        C[(size_t)(row0 + r) * N + col] = f2bf(sw * v3);
      }
    }
  }
}

// ---------------- split-precision GEMM (Q/K projection), BK=32 -------------
// acc += Ahi*Bhi + Ahi*Blo + Alo*Bhi  (drops lo*lo: ~2^-18 relative)
// R0-verified epilogue (no pre-scale; flash applies 0.125 itself).

__global__ __launch_bounds__(256) void gemm_bt_split_k(
    const uint16_t* __restrict__ Ahi, const uint16_t* __restrict__ Alo,
    const uint16_t* __restrict__ Bhi, const uint16_t* __restrict__ Blo,
    uint16_t* __restrict__ Chi, uint16_t* __restrict__ Clo, int N, int K) {
  __shared__ __align__(16) uint16_t Ah[128 * 32];
  __shared__ __align__(16) uint16_t Al[128 * 32];
  __shared__ __align__(16) uint16_t Bh[128 * 32];
  __shared__ __align__(16) uint16_t Bl[128 * 32];
  const int t = threadIdx.x, w = t >> 6, lane = t & 63, m16 = lane & 15, quad = lane >> 4;
  const int wm = (w >> 1) * 64, wn = (w & 1) * 64;
  const int mBase = blockIdx.y * 128, nBase = blockIdx.x * 128;
  f32x4 acc[4][4];
  const f32x4 vz = {0.f, 0.f, 0.f, 0.f};
#pragma unroll
  for (int i = 0; i < 4; ++i)
#pragma unroll
    for (int j = 0; j < 4; ++j) acc[i][j] = vz;
  const int r_ = t >> 2, g_ = t & 3, sg = g_ ^ (r_ & 3);   // (it*64) % 4 == 0
  const uint16_t* agh = Ahi + (size_t)(mBase + r_) * K + sg * 8;
  const uint16_t* agl = Alo + (size_t)(mBase + r_) * K + sg * 8;
  const uint16_t* bgh = Bhi + (size_t)(nBase + r_) * K + sg * 8;
  const uint16_t* bgl = Blo + (size_t)(nBase + r_) * K + sg * 8;
  for (int k0 = 0; k0 < K; k0 += 32) {
#pragma unroll
    for (int it = 0; it < 2; ++it) {
      gl_lds16(agh + (size_t)(it * 64) * K + k0, Ah + it * 2048 + t * 8);
      gl_lds16(agl + (size_t)(it * 64) * K + k0, Al + it * 2048 + t * 8);
      gl_lds16(bgh + (size_t)(it * 64) * K + k0, Bh + it * 2048 + t * 8);
      gl_lds16(bgl + (size_t)(it * 64) * K + k0, Bl + it * 2048 + t * 8);
    }
    __syncthreads();
    bf16x8 ah[4], al[4], bh4[4], bl4[4];
#pragma unroll
    for (int i = 0; i < 4; ++i) {
      const int rA = wm + i * 16 + m16;
      const int offA = rA * 32 + ((quad ^ (rA & 3)) * 8);
      ah[i] = *(const bf16x8*)(Ah + offA);
      al[i] = *(const bf16x8*)(Al + offA);
      const int rB = wn + i * 16 + m16;
      const int offB = rB * 32 + ((quad ^ (rB & 3)) * 8);
      bh4[i] = *(const bf16x8*)(Bh + offB);
      bl4[i] = *(const bf16x8*)(Bl + offB);
    }
#pragma unroll
    for (int i = 0; i < 4; ++i)
#pragma unroll
      for (int j = 0; j < 4; ++j) {
        acc[i][j] = __builtin_amdgcn_mfma_f32_16x16x32_bf16(ah[i], bh4[j], acc[i][j], 0, 0, 0);
        acc[i][j] = __builtin_amdgcn_mfma_f32_16x16x32_bf16(ah[i], bl4[j], acc[i][j], 0, 0, 0);
        acc[i][j] = __builtin_amdgcn_mfma_f32_16x16x32_bf16(al[i], bh4[j], acc[i][j], 0, 0, 0);
      }
    __syncthreads();
  }
#pragma unroll
  for (int i = 0; i < 4; ++i) {
    const int row0 = mBase + wm + i * 16 + quad * 4;
#pragma unroll
    for (int j = 0; j < 4; ++j) {
      const int col = nBase + wn + j * 16 + m16;
#pragma unroll
      for (int r = 0; r < 4; ++r) {
        const size_t idx = (size_t)(row0 + r) * N + col;
        const float v = acc[i][j][r];
        const uint16_t hh = f2bf(v);
        Chi[idx] = hh;
        Clo[idx] = f2bf(v - bf2f(hh));
      }
    }
  }
}

// ---------------------------------- RoPE -----------------------------------
// In-place on split QK buffer [8192][2048] (cols 0..1023 Q, 1024..2047 K).

__global__ __launch_bounds__(256) void rope_k(uint16_t* __restrict__ qkh,
                                              uint16_t* __restrict__ qkl,
                                              const int* __restrict__ pos) {
  const int t = blockIdx.x * 256 + threadIdx.x;   // 8192*1024 pairs
  const int row = t >> 10, p = t & 1023;
  const int which = p >> 9, hp = p & 511, h = hp >> 5, d2 = hp & 31;
  const size_t idx = (size_t)row * 2048 + which * 1024 + h * 64 + d2 * 2;
  const uint32_t ph = *(const uint32_t*)(qkh + idx);
  const uint32_t pl = *(const uint32_t*)(qkl + idx);
  const float xe = bf2f(ph & 0xffffu) + bf2f(pl & 0xffffu);
  const float xo = bf2f(ph >> 16) + bf2f(pl >> 16);
  // inv_freq = 10000^(-d2/32) = exp2(-d2 * log2(10000)/32)
  const float inv_freq = exp2f((float)d2 * -0.41524101186092029f);
  const float fr = (float)pos[row & 2047] * inv_freq;
  float sn, cs; sincosf(fr, &sn, &cs);
  const float re = xe * cs - xo * sn;
  const float ro = xe * sn + xo * cs;
  const uint16_t reh = f2bf(re), roh = f2bf(ro);
  const uint16_t rel = f2bf(re - bf2f(reh)), rol = f2bf(ro - bf2f(roh));
  *(uint32_t*)(qkh + idx) = (uint32_t)reh | ((uint32_t)roh << 16);
  *(uint32_t*)(qkl + idx) = (uint32_t)rel | ((uint32_t)rol << 16);
}

// ------------------------- V transpose: [s][d] -> [d][s] --------------------

__global__ __launch_bounds__(256) void transpose_v_k(const uint16_t* __restrict__ V,
                                                     uint16_t* __restrict__ Vt) {
  __shared__ __align__(16) uint16_t tile[64][72];
  const int st = blockIdx.x, bh = blockIdx.y, b = bh >> 4, h = bh & 15;
  const int t = threadIdx.x;
  {
    const int sl = t >> 3, dg = t & 7;
#pragma unroll
    for (int it = 0; it < 2; ++it) {
      const int s = it * 32 + sl;
      const uint4 v = *(const uint4*)(V + (size_t)(b * 2048 + st * 64 + s) * 1024 + h * 64 + dg * 8);
      *(uint4*)(&tile[s][dg * 8]) = v;
    }
  }
  __syncthreads();
  {
    const int dl = t >> 3, sg2 = t & 7;
#pragma unroll
    for (int it = 0; it < 2; ++it) {
      const int d = it * 32 + dl;
      union { uint4 v; uint16_t u[8]; } pk;
#pragma unroll
      for (int r = 0; r < 8; ++r) pk.u[r] = tile[sg2 * 8 + r][d];
      *(uint4*)(Vt + (size_t)(bh * 64 + d) * 2048 + st * 64 + sg2 * 8) = pk.v;
    }
  }
}

// ----------------------- causal flash attention -----------------------------
// R0-VERIFIED VERSION (308 us, absmax 32). BQ=128 (4 waves x 32 rows),
// BKV=64, d_head=64. QK^T split 3-pass, PV bf16. Single-buffer staging.

__global__ __launch_bounds__(256) void flash_k(const uint16_t* __restrict__ Qh,
                                               const uint16_t* __restrict__ Ql,
                                               const uint16_t* __restrict__ Vt,
                                               uint16_t* __restrict__ Hout) {
  __shared__ __align__(16) uint16_t Kh[64 * 64];
  __shared__ __align__(16) uint16_t Kl[64 * 64];
  __shared__ __align__(16) uint16_t Vs[64 * 64];
  __shared__ __align__(16) uint16_t P[4][32 * 72];

  const int qt = blockIdx.x, bh = blockIdx.y, b = bh >> 4, h = bh & 15;
  const int t = threadIdx.x, w = t >> 6, lane = t & 63, m16 = lane & 15, quad = lane >> 4;

  bf16x8 qh[2][2], ql[2][2];
#pragma unroll
  for (int i = 0; i < 2; ++i) {
    const int row = b * 2048 + qt * 128 + w * 32 + i * 16 + m16;
#pragma unroll
    for (int ks = 0; ks < 2; ++ks) {
      const size_t offq = (size_t)row * 2048 + h * 64 + ks * 32 + quad * 8;
      qh[i][ks] = *(const bf16x8*)(Qh + offq);
      ql[i][ks] = *(const bf16x8*)(Ql + offq);
    }
  }

  float mr[2][4], lr[2][4];
  f32x4 o[2][4];
  const f32x4 vz = {0.f, 0.f, 0.f, 0.f};
#pragma unroll
  for (int i = 0; i < 2; ++i)
#pragma unroll
    for (int r = 0; r < 4; ++r) { mr[i][r] = -1e30f; lr[i][r] = 0.f; }
#pragma unroll
  for (int i = 0; i < 2; ++i)
#pragma unroll
    for (int n = 0; n < 4; ++n) o[i][n] = vz;

  const int r_ = t >> 3, g_ = t & 7, sgx = g_ ^ (r_ & 7);
  const uint16_t* khg = Qh + (size_t)(b * 2048 + r_) * 2048 + 1024 + h * 64 + sgx * 8;
  const uint16_t* klg = Ql + (size_t)(b * 2048 + r_) * 2048 + 1024 + h * 64 + sgx * 8;
  const uint16_t* vtg = Vt + (size_t)(bh * 64 + r_) * 2048 + sgx * 8;

  const int ktEnd = 2 * qt + 2;
  for (int kt = 0; kt < ktEnd; ++kt) {
#pragma unroll
    for (int it = 0; it < 2; ++it) {
      gl_lds16(khg + (size_t)(kt * 64 + it * 32) * 2048, Kh + it * 2048 + t * 8);
      gl_lds16(klg + (size_t)(kt * 64 + it * 32) * 2048, Kl + it * 2048 + t * 8);
      gl_lds16(vtg + (size_t)(it * 32) * 2048 + kt * 64, Vs + it * 2048 + t * 8);
    }
    __syncthreads();

    f32x4 sc[2][4];
#pragma unroll
    for (int i = 0; i < 2; ++i)
#pragma unroll
      for (int j = 0; j < 4; ++j) sc[i][j] = vz;
#pragma unroll
    for (int ks = 0; ks < 2; ++ks) {
      bf16x8 kfh[4], kfl[4];
      const int cg = ks * 4 + quad;
#pragma unroll
      for (int j = 0; j < 4; ++j) {
        const int rK = j * 16 + m16;
        const int offk = rK * 64 + ((cg ^ (rK & 7)) * 8);
        kfh[j] = *(const bf16x8*)(Kh + offk);
        kfl[j] = *(const bf16x8*)(Kl + offk);
      }
#pragma unroll
      for (int i = 0; i < 2; ++i)
#pragma unroll
        for (int j = 0; j < 4; ++j) {
          sc[i][j] = __builtin_amdgcn_mfma_f32_16x16x32_bf16(qh[i][ks], kfh[j], sc[i][j], 0, 0, 0);
          sc[i][j] = __builtin_amdgcn_mfma_f32_16x16x32_bf16(qh[i][ks], kfl[j], sc[i][j], 0, 0, 0);
          sc[i][j] = __builtin_amdgcn_mfma_f32_16x16x32_bf16(ql[i][ks], kfh[j], sc[i][j], 0, 0, 0);
        }
    }

#pragma unroll
    for (int i = 0; i < 2; ++i) {
#pragma unroll
      for (int r = 0; r < 4; ++r) {
        const int qg = qt * 128 + w * 32 + i * 16 + quad * 4 + r;
        float mx = -1e30f;
#pragma unroll
        for (int j = 0; j < 4; ++j) {
          float v = sc[i][j][r] * 0.125f;
          const int kg = kt * 64 + j * 16 + m16;
          if (kg > qg) v = -1e30f;
          sc[i][j][r] = v;
          mx = fmaxf(mx, v);
        }
#pragma unroll
        for (int m = 1; m < 16; m <<= 1) mx = fmaxf(mx, __shfl_xor(mx, m));
        const float mnew = fmaxf(mr[i][r], mx);
        const float alpha = __expf(mr[i][r] - mnew);
        mr[i][r] = mnew;
        float ls = 0.f;
#pragma unroll
        for (int j = 0; j < 4; ++j) {
          const float pv = __expf(sc[i][j][r] - mnew);
          sc[i][j][r] = pv;
          ls += pv;
        }
#pragma unroll
        for (int m = 1; m < 16; m <<= 1) ls += __shfl_xor(ls, m);
        lr[i][r] = lr[i][r] * alpha + ls;
#pragma unroll
        for (int n = 0; n < 4; ++n) o[i][n][r] *= alpha;
      }
#pragma unroll
      for (int j = 0; j < 4; ++j)
#pragma unroll
        for (int r = 0; r < 4; ++r)
          P[w][(i * 16 + quad * 4 + r) * 72 + j * 16 + m16] = f2bf(sc[i][j][r]);
    }
    __syncthreads();

#pragma unroll
    for (int ks2 = 0; ks2 < 2; ++ks2) {
      bf16x8 pf[2], vf[4];
#pragma unroll
      for (int i = 0; i < 2; ++i)
        pf[i] = *(const bf16x8*)(&P[w][(i * 16 + m16) * 72 + ks2 * 32 + quad * 8]);
      const int cg = ks2 * 4 + quad;
#pragma unroll
      for (int n = 0; n < 4; ++n) {
        const int rV = n * 16 + m16;
        vf[n] = *(const bf16x8*)(Vs + rV * 64 + ((cg ^ (rV & 7)) * 8));
      }
#pragma unroll
      for (int i = 0; i < 2; ++i)
#pragma unroll
        for (int n = 0; n < 4; ++n)
          o[i][n] = __builtin_amdgcn_mfma_f32_16x16x32_bf16(pf[i], vf[n], o[i][n], 0, 0, 0);
    }
    __syncthreads();
  }

#pragma unroll
  for (int i = 0; i < 2; ++i)
#pragma unroll
    for (int r = 0; r < 4; ++r) {
      const float inv = 1.f / lr[i][r];
      const size_t row = (size_t)(b * 2048 + qt * 128 + w * 32 + i * 16 + quad * 4 + r);
#pragma unroll
      for (int n = 0; n < 4; ++n)
        Hout[row * 1024 + h * 64 + n * 16 + m16] = f2bf(o[i][n][r] * inv);
    }
}

// ------------------------------ orchestration -------------------------------

extern "C" void kernel_launch(void* const* d_in, const int* in_sizes, int n_in,
                              void* d_out, int out_size, void* d_ws, size_t ws_size,
                              hipStream_t stream) {
  (void)in_sizes; (void)n_in; (void)out_size; (void)ws_size;
  const float* x   = (const float*)d_in[0];
  const int*   pos = (const int*)  d_in[1];
  const float* q_w = (const float*)d_in[2];
  const float* k_w = (const float*)d_in[3];
  const float* v_w = (const float*)d_in[4];
  const float* o_w = (const float*)d_in[5];
  const float* g1  = (const float*)d_in[6];
  const float* g2  = (const float*)d_in[7];
  const float* w1  = (const float*)d_in[8];
  const float* w2  = (const float*)d_in[9];
  const float* w3  = (const float*)d_in[10];

  char* ws = (char*)d_ws;
  uint16_t* wqk_hi = (uint16_t*)(ws + 0);
  uint16_t* wqk_lo = (uint16_t*)(ws + 4194304);
  uint16_t* wv     = (uint16_t*)(ws + 8388608);
  uint16_t* wo     = (uint16_t*)(ws + 10485760);
  uint16_t* w1b    = (uint16_t*)(ws + 12582912);
  uint16_t* w3b    = (uint16_t*)(ws + 20971520);
  uint16_t* w2b    = (uint16_t*)(ws + 29360128);
  uint16_t* xn_hi  = (uint16_t*)(ws + 37748736);
  uint16_t* xn_lo  = (uint16_t*)(ws + 54525952);
  uint16_t* vbuf   = (uint16_t*)(ws + 71303168);
  uint16_t* vt     = (uint16_t*)(ws + 88080384);
  uint16_t* qk_hi  = (uint16_t*)(ws + 104857600);
  uint16_t* qk_lo  = (uint16_t*)(ws + 138412032);
  uint16_t* hbuf   = (uint16_t*)(ws + 171966464);
  float*    ores   = (float*)   (ws + 188743680);
  uint16_t* on2    = (uint16_t*)(ws + 222298112);
  // overlay (region dead by the time this is written):
  uint16_t* abuf   = (uint16_t*)(ws + 104857600);  // over qk_hi+qk_lo (67.1 MB)
  // total ws required: 239,075,328 bytes

  cvt_split_qk_k<<<2048, 256, 0, stream>>>(q_w, k_w, wqk_hi, wqk_lo);
  cvt_bf16_k<<<1024, 256, 0, stream>>>(v_w, wv, 262144);
  cvt_bf16_k<<<1024, 256, 0, stream>>>(o_w, wo, 262144);
  cvt_bf16_k<<<4096, 256, 0, stream>>>(w1, w1b, 1048576);
  cvt_bf16_k<<<4096, 256, 0, stream>>>(w3, w3b, 1048576);
  cvt_bf16_k<<<4096, 256, 0, stream>>>(w2, w2b, 1048576);

  rmsnorm_k<true><<<8192, 256, 0, stream>>>(x, g1, xn_hi, xn_lo);

  gemm_bt_split_k<<<dim3(16, 64), 256, 0, stream>>>(xn_hi, xn_lo, wqk_hi, wqk_lo,
                                                    qk_hi, qk_lo, 2048, 1024);
  gemm_bt_k<0><<<dim3(8, 64), 256, 0, stream>>>(xn_hi, wv, (void*)vbuf, nullptr, 1024, 1024);

  rope_k<<<32768, 256, 0, stream>>>(qk_hi, qk_lo, pos);
  transpose_v_k<<<dim3(32, 64), 256, 0, stream>>>(vbuf, vt);

  flash_k<<<dim3(16, 64), 256, 0, stream>>>(qk_hi, qk_lo, vt, hbuf);

  gemm_bt_k<1><<<dim3(8, 64), 256, 0, stream>>>(hbuf, wo, (void*)ores, x, 1024, 1024);

  rmsnorm_k<false><<<8192, 256, 0, stream>>>(ores, g2, on2, nullptr);

  gemm_ffn13_k<<<dim3(32, 64), 256, 0, stream>>>(on2, w1b, w3b, abuf);

  gemm_bt_k<1><<<dim3(8, 64), 256, 0, stream>>>(abuf, w2b, d_out, ores, 1024, 4096);
}

// Round 6
// 911.215 us; speedup vs baseline: 1.0682x; 1.0682x over previous
//
#include <hip/hip_runtime.h>
#include <stdint.h>

// ---------------------------------------------------------------------------
// TransformerBlock: rmsnorm -> QKV -> RoPE -> causal flash attn -> +x ->
//                   rmsnorm -> swiglu FFN -> +O
// bf16 MFMA everywhere; Q/K path uses hi/lo bf16 split (3-pass MFMA) because
// softmax is near-one-hot on scores with sigma~900.
// R6: (a) flash_k load balance - grid (8,64), each block processes q-tile
// PAIR (qt, 15-qt) = exactly 34 KV-iters per block (was 2..32, tail-bound at
// 10.9% occupancy). Inner loop is the R0-verified body verbatim.
// (b) reverted R5's ffn13 fusion (measured +60 us regression: 128 acc VGPRs
// neared the 256 cliff) back to R2's separate w1/w3 GEMMs + swiglu.
// ---------------------------------------------------------------------------

typedef short bf16x8 __attribute__((ext_vector_type(8)));
typedef float f32x4  __attribute__((ext_vector_type(4)));

#define DEV static __device__ __forceinline__

DEV float bf2f(uint32_t u) { uint32_t v = u << 16; float f; __builtin_memcpy(&f, &v, 4); return f; }
DEV uint16_t f2bf(float f) {
  uint32_t u; __builtin_memcpy(&u, &f, 4);
  u = (u + 0x7fffu + ((u >> 16) & 1u)) >> 16;   // RNE
  return (uint16_t)u;
}

DEV void gl_lds16(const uint16_t* g, uint16_t* l) {
  __builtin_amdgcn_global_load_lds((const __attribute__((address_space(1))) uint32_t*)g,
                                   (__attribute__((address_space(3))) uint32_t*)l, 16, 0, 0);
}

// ---------------------------- weight conversion ----------------------------

__global__ __launch_bounds__(256) void cvt_bf16_k(const float* __restrict__ src,
                                                  uint16_t* __restrict__ dst, int n4) {
  const int t = blockIdx.x * 256 + threadIdx.x;
  if (t >= n4) return;
  const float4 v = ((const float4*)src)[t];
  ushort4 o; o.x = f2bf(v.x); o.y = f2bf(v.y); o.z = f2bf(v.z); o.w = f2bf(v.w);
  ((ushort4*)dst)[t] = o;
}

__global__ __launch_bounds__(256) void cvt_split_qk_k(const float* __restrict__ qw,
                                                      const float* __restrict__ kw,
                                                      uint16_t* __restrict__ hi,
                                                      uint16_t* __restrict__ lo) {
  const int t = blockIdx.x * 256 + threadIdx.x;    // 2048*256 float4s
  const int row = t >> 8, c4 = t & 255;
  const float* src = (row < 1024) ? (qw + (size_t)row * 1024)
                                  : (kw + (size_t)(row - 1024) * 1024);
  const float4 v = ((const float4*)src)[c4];
  ushort4 h, l;
  h.x = f2bf(v.x); l.x = f2bf(v.x - bf2f(h.x));
  h.y = f2bf(v.y); l.y = f2bf(v.y - bf2f(h.y));
  h.z = f2bf(v.z); l.z = f2bf(v.z - bf2f(h.z));
  h.w = f2bf(v.w); l.w = f2bf(v.w - bf2f(h.w));
  ((ushort4*)hi)[t] = h; ((ushort4*)lo)[t] = l;
}

// -------------------------------- rmsnorm ----------------------------------

template <bool SPLIT>
__global__ __launch_bounds__(256) void rmsnorm_k(const float* __restrict__ xin,
                                                 const float* __restrict__ g,
                                                 uint16_t* __restrict__ hi,
                                                 uint16_t* __restrict__ lo) {
  const int row = blockIdx.x, t = threadIdx.x;
  const float4 v = ((const float4*)(xin + (size_t)row * 1024))[t];
  float ss = v.x * v.x + v.y * v.y + v.z * v.z + v.w * v.w;
#pragma unroll
  for (int m = 1; m < 64; m <<= 1) ss += __shfl_xor(ss, m);
  __shared__ float red[4];
  if ((t & 63) == 0) red[t >> 6] = ss;
  __syncthreads();
  const float rinv = rsqrtf((red[0] + red[1] + red[2] + red[3]) * (1.0f / 1024.0f) + 1e-5f);
  const float4 gv = ((const float4*)g)[t];
  float y[4] = { v.x * rinv * gv.x, v.y * rinv * gv.y, v.z * rinv * gv.z, v.w * rinv * gv.w };
  ushort4 h; h.x = f2bf(y[0]); h.y = f2bf(y[1]); h.z = f2bf(y[2]); h.w = f2bf(y[3]);
  ((ushort4*)(hi + (size_t)row * 1024))[t] = h;
  if constexpr (SPLIT) {
    ushort4 l;
    l.x = f2bf(y[0] - bf2f(h.x)); l.y = f2bf(y[1] - bf2f(h.y));
    l.z = f2bf(y[2] - bf2f(h.z)); l.w = f2bf(y[3] - bf2f(h.w));
    ((ushort4*)(lo + (size_t)row * 1024))[t] = l;
  }
}

// ------------------------ GEMM  C[M,N] = A[M,K] @ B[N,K]^T ------------------
// 128x128 tile, BK=64, 4 waves (2x2), 16x16x32 bf16 MFMA.
// LDS tiles XOR-swizzled: slot [r][g] holds global colgrp g^(r&7).

template <int OUT>   // 0: bf16 out; 1: f32 out + residual add
__global__ __launch_bounds__(256) void gemm_bt_k(const uint16_t* __restrict__ A,
                                                 const uint16_t* __restrict__ B,
                                                 void* __restrict__ C,
                                                 const float* __restrict__ resid,
                                                 int N, int K) {
  __shared__ __align__(16) uint16_t As[128 * 64];
  __shared__ __align__(16) uint16_t Bs[128 * 64];
  const int t = threadIdx.x, w = t >> 6, lane = t & 63, m16 = lane & 15, quad = lane >> 4;
  const int wm = (w >> 1) * 64, wn = (w & 1) * 64;
  const int mBase = blockIdx.y * 128, nBase = blockIdx.x * 128;
  f32x4 acc[4][4];
  const f32x4 vz = {0.f, 0.f, 0.f, 0.f};
#pragma unroll
  for (int i = 0; i < 4; ++i)
#pragma unroll
    for (int j = 0; j < 4; ++j) acc[i][j] = vz;
  const int r_ = t >> 3, g_ = t & 7, sg = g_ ^ (r_ & 7);   // (it*32) % 8 == 0
  const uint16_t* ag = A + (size_t)(mBase + r_) * K + sg * 8;
  const uint16_t* bg = B + (size_t)(nBase + r_) * K + sg * 8;
  for (int k0 = 0; k0 < K; k0 += 64) {
#pragma unroll
    for (int it = 0; it < 4; ++it) {
      gl_lds16(ag + (size_t)(it * 32) * K + k0, As + it * 2048 + t * 8);
      gl_lds16(bg + (size_t)(it * 32) * K + k0, Bs + it * 2048 + t * 8);
    }
    __syncthreads();
#pragma unroll
    for (int ks = 0; ks < 2; ++ks) {
      bf16x8 af[4], bf4[4];
      const int cg = ks * 4 + quad;
#pragma unroll
      for (int i = 0; i < 4; ++i) {
        const int rA = wm + i * 16 + m16;
        af[i] = *(const bf16x8*)(As + rA * 64 + ((cg ^ (rA & 7)) * 8));
        const int rB = wn + i * 16 + m16;
        bf4[i] = *(const bf16x8*)(Bs + rB * 64 + ((cg ^ (rB & 7)) * 8));
      }
#pragma unroll
      for (int i = 0; i < 4; ++i)
#pragma unroll
        for (int j = 0; j < 4; ++j)
          acc[i][j] = __builtin_amdgcn_mfma_f32_16x16x32_bf16(af[i], bf4[j], acc[i][j], 0, 0, 0);
    }
    __syncthreads();
  }
#pragma unroll
  for (int i = 0; i < 4; ++i) {
    const int row0 = mBase + wm + i * 16 + quad * 4;
#pragma unroll
    for (int j = 0; j < 4; ++j) {
      const int col = nBase + wn + j * 16 + m16;
#pragma unroll
      for (int r = 0; r < 4; ++r) {
        const size_t idx = (size_t)(row0 + r) * N + col;
        const float v = acc[i][j][r];
        if constexpr (OUT == 1) ((float*)C)[idx] = v + resid[idx];
        else                    ((uint16_t*)C)[idx] = f2bf(v);
      }
    }
  }
}

// ---------------- split-precision GEMM (Q/K projection), BK=32 -------------
// acc += Ahi*Bhi + Ahi*Blo + Alo*Bhi  (drops lo*lo: ~2^-18 relative)

__global__ __launch_bounds__(256) void gemm_bt_split_k(
    const uint16_t* __restrict__ Ahi, const uint16_t* __restrict__ Alo,
    const uint16_t* __restrict__ Bhi, const uint16_t* __restrict__ Blo,
    uint16_t* __restrict__ Chi, uint16_t* __restrict__ Clo, int N, int K) {
  __shared__ __align__(16) uint16_t Ah[128 * 32];
  __shared__ __align__(16) uint16_t Al[128 * 32];
  __shared__ __align__(16) uint16_t Bh[128 * 32];
  __shared__ __align__(16) uint16_t Bl[128 * 32];
  const int t = threadIdx.x, w = t >> 6, lane = t & 63, m16 = lane & 15, quad = lane >> 4;
  const int wm = (w >> 1) * 64, wn = (w & 1) * 64;
  const int mBase = blockIdx.y * 128, nBase = blockIdx.x * 128;
  f32x4 acc[4][4];
  const f32x4 vz = {0.f, 0.f, 0.f, 0.f};
#pragma unroll
  for (int i = 0; i < 4; ++i)
#pragma unroll
    for (int j = 0; j < 4; ++j) acc[i][j] = vz;
  const int r_ = t >> 2, g_ = t & 3, sg = g_ ^ (r_ & 3);   // (it*64) % 4 == 0
  const uint16_t* agh = Ahi + (size_t)(mBase + r_) * K + sg * 8;
  const uint16_t* agl = Alo + (size_t)(mBase + r_) * K + sg * 8;
  const uint16_t* bgh = Bhi + (size_t)(nBase + r_) * K + sg * 8;
  const uint16_t* bgl = Blo + (size_t)(nBase + r_) * K + sg * 8;
  for (int k0 = 0; k0 < K; k0 += 32) {
#pragma unroll
    for (int it = 0; it < 2; ++it) {
      gl_lds16(agh + (size_t)(it * 64) * K + k0, Ah + it * 2048 + t * 8);
      gl_lds16(agl + (size_t)(it * 64) * K + k0, Al + it * 2048 + t * 8);
      gl_lds16(bgh + (size_t)(it * 64) * K + k0, Bh + it * 2048 + t * 8);
      gl_lds16(bgl + (size_t)(it * 64) * K + k0, Bl + it * 2048 + t * 8);
    }
    __syncthreads();
    bf16x8 ah[4], al[4], bh4[4], bl4[4];
#pragma unroll
    for (int i = 0; i < 4; ++i) {
      const int rA = wm + i * 16 + m16;
      const int offA = rA * 32 + ((quad ^ (rA & 3)) * 8);
      ah[i] = *(const bf16x8*)(Ah + offA);
      al[i] = *(const bf16x8*)(Al + offA);
      const int rB = wn + i * 16 + m16;
      const int offB = rB * 32 + ((quad ^ (rB & 3)) * 8);
      bh4[i] = *(const bf16x8*)(Bh + offB);
      bl4[i] = *(const bf16x8*)(Bl + offB);
    }
#pragma unroll
    for (int i = 0; i < 4; ++i)
#pragma unroll
      for (int j = 0; j < 4; ++j) {
        acc[i][j] = __builtin_amdgcn_mfma_f32_16x16x32_bf16(ah[i], bh4[j], acc[i][j], 0, 0, 0);
        acc[i][j] = __builtin_amdgcn_mfma_f32_16x16x32_bf16(ah[i], bl4[j], acc[i][j], 0, 0, 0);
        acc[i][j] = __builtin_amdgcn_mfma_f32_16x16x32_bf16(al[i], bh4[j], acc[i][j], 0, 0, 0);
      }
    __syncthreads();
  }
#pragma unroll
  for (int i = 0; i < 4; ++i) {
    const int row0 = mBase + wm + i * 16 + quad * 4;
#pragma unroll
    for (int j = 0; j < 4; ++j) {
      const int col = nBase + wn + j * 16 + m16;
#pragma unroll
      for (int r = 0; r < 4; ++r) {
        const size_t idx = (size_t)(row0 + r) * N + col;
        const float v = acc[i][j][r];
        const uint16_t hh = f2bf(v);
        Chi[idx] = hh;
        Clo[idx] = f2bf(v - bf2f(hh));
      }
    }
  }
}

// ---------------------------------- RoPE -----------------------------------
// In-place on split QK buffer [8192][2048] (cols 0..1023 Q, 1024..2047 K).

__global__ __launch_bounds__(256) void rope_k(uint16_t* __restrict__ qkh,
                                              uint16_t* __restrict__ qkl,
                                              const int* __restrict__ pos) {
  const int t = blockIdx.x * 256 + threadIdx.x;   // 8192*1024 pairs
  const int row = t >> 10, p = t & 1023;
  const int which = p >> 9, hp = p & 511, h = hp >> 5, d2 = hp & 31;
  const size_t idx = (size_t)row * 2048 + which * 1024 + h * 64 + d2 * 2;
  const uint32_t ph = *(const uint32_t*)(qkh + idx);
  const uint32_t pl = *(const uint32_t*)(qkl + idx);
  const float xe = bf2f(ph & 0xffffu) + bf2f(pl & 0xffffu);
  const float xo = bf2f(ph >> 16) + bf2f(pl >> 16);
  // inv_freq = 10000^(-d2/32) = exp2(-d2 * log2(10000)/32)
  const float inv_freq = exp2f((float)d2 * -0.41524101186092029f);
  const float fr = (float)pos[row & 2047] * inv_freq;
  float sn, cs; sincosf(fr, &sn, &cs);
  const float re = xe * cs - xo * sn;
  const float ro = xe * sn + xo * cs;
  const uint16_t reh = f2bf(re), roh = f2bf(ro);
  const uint16_t rel = f2bf(re - bf2f(reh)), rol = f2bf(ro - bf2f(roh));
  *(uint32_t*)(qkh + idx) = (uint32_t)reh | ((uint32_t)roh << 16);
  *(uint32_t*)(qkl + idx) = (uint32_t)rel | ((uint32_t)rol << 16);
}

// ------------------------- V transpose: [s][d] -> [d][s] --------------------

__global__ __launch_bounds__(256) void transpose_v_k(const uint16_t* __restrict__ V,
                                                     uint16_t* __restrict__ Vt) {
  __shared__ __align__(16) uint16_t tile[64][72];
  const int st = blockIdx.x, bh = blockIdx.y, b = bh >> 4, h = bh & 15;
  const int t = threadIdx.x;
  {
    const int sl = t >> 3, dg = t & 7;
#pragma unroll
    for (int it = 0; it < 2; ++it) {
      const int s = it * 32 + sl;
      const uint4 v = *(const uint4*)(V + (size_t)(b * 2048 + st * 64 + s) * 1024 + h * 64 + dg * 8);
      *(uint4*)(&tile[s][dg * 8]) = v;
    }
  }
  __syncthreads();
  {
    const int dl = t >> 3, sg2 = t & 7;
#pragma unroll
    for (int it = 0; it < 2; ++it) {
      const int d = it * 32 + dl;
      union { uint4 v; uint16_t u[8]; } pk;
#pragma unroll
      for (int r = 0; r < 8; ++r) pk.u[r] = tile[sg2 * 8 + r][d];
      *(uint4*)(Vt + (size_t)(bh * 64 + d) * 2048 + st * 64 + sg2 * 8) = pk.v;
    }
  }
}

// ----------------------- causal flash attention -----------------------------
// R0-VERIFIED inner loop. R6: grid (8,64); each block processes the q-tile
// PAIR (qt, 15-qt) sequentially = exactly 34 KV-iterations per block, killing
// the causal load-imbalance tail (was 2..32 iters across blocks).

__global__ __launch_bounds__(256) void flash_k(const uint16_t* __restrict__ Qh,
                                               const uint16_t* __restrict__ Ql,
                                               const uint16_t* __restrict__ Vt,
                                               uint16_t* __restrict__ Hout) {
  __shared__ __align__(16) uint16_t Kh[64 * 64];
  __shared__ __align__(16) uint16_t Kl[64 * 64];
  __shared__ __align__(16) uint16_t Vs[64 * 64];
  __shared__ __align__(16) uint16_t P[4][32 * 72];

  const int bh = blockIdx.y, b = bh >> 4, h = bh & 15;
  const int t = threadIdx.x, w = t >> 6, lane = t & 63, m16 = lane & 15, quad = lane >> 4;

  const int r_ = t >> 3, g_ = t & 7, sgx = g_ ^ (r_ & 7);
  const uint16_t* khg = Qh + (size_t)(b * 2048 + r_) * 2048 + 1024 + h * 64 + sgx * 8;
  const uint16_t* klg = Ql + (size_t)(b * 2048 + r_) * 2048 + 1024 + h * 64 + sgx * 8;
  const uint16_t* vtg = Vt + (size_t)(bh * 64 + r_) * 2048 + sgx * 8;

  for (int half = 0; half < 2; ++half) {
    const int qt = half ? (15 - (int)blockIdx.x) : (int)blockIdx.x;

    bf16x8 qh[2][2], ql[2][2];
#pragma unroll
    for (int i = 0; i < 2; ++i) {
      const int row = b * 2048 + qt * 128 + w * 32 + i * 16 + m16;
#pragma unroll
      for (int ks = 0; ks < 2; ++ks) {
        const size_t offq = (size_t)row * 2048 + h * 64 + ks * 32 + quad * 8;
        qh[i][ks] = *(const bf16x8*)(Qh + offq);
        ql[i][ks] = *(const bf16x8*)(Ql + offq);
      }
    }

    float mr[2][4], lr[2][4];
    f32x4 o[2][4];
    const f32x4 vz = {0.f, 0.f, 0.f, 0.f};
#pragma unroll
    for (int i = 0; i < 2; ++i)
#pragma unroll
      for (int r = 0; r < 4; ++r) { mr[i][r] = -1e30f; lr[i][r] = 0.f; }
#pragma unroll
    for (int i = 0; i < 2; ++i)
#pragma unroll
      for (int n = 0; n < 4; ++n) o[i][n] = vz;

    const int ktEnd = 2 * qt + 2;
    for (int kt = 0; kt < ktEnd; ++kt) {
#pragma unroll
      for (int it = 0; it < 2; ++it) {
        gl_lds16(khg + (size_t)(kt * 64 + it * 32) * 2048, Kh + it * 2048 + t * 8);
        gl_lds16(klg + (size_t)(kt * 64 + it * 32) * 2048, Kl + it * 2048 + t * 8);
        gl_lds16(vtg + (size_t)(it * 32) * 2048 + kt * 64, Vs + it * 2048 + t * 8);
      }
      __syncthreads();

      f32x4 sc[2][4];
#pragma unroll
      for (int i = 0; i < 2; ++i)
#pragma unroll
        for (int j = 0; j < 4; ++j) sc[i][j] = vz;
#pragma unroll
      for (int ks = 0; ks < 2; ++ks) {
        bf16x8 kfh[4], kfl[4];
        const int cg = ks * 4 + quad;
#pragma unroll
        for (int j = 0; j < 4; ++j) {
          const int rK = j * 16 + m16;
          const int offk = rK * 64 + ((cg ^ (rK & 7)) * 8);
          kfh[j] = *(const bf16x8*)(Kh + offk);
          kfl[j] = *(const bf16x8*)(Kl + offk);
        }
#pragma unroll
        for (int i = 0; i < 2; ++i)
#pragma unroll
          for (int j = 0; j < 4; ++j) {
            sc[i][j] = __builtin_amdgcn_mfma_f32_16x16x32_bf16(qh[i][ks], kfh[j], sc[i][j], 0, 0, 0);
            sc[i][j] = __builtin_amdgcn_mfma_f32_16x16x32_bf16(qh[i][ks], kfl[j], sc[i][j], 0, 0, 0);
            sc[i][j] = __builtin_amdgcn_mfma_f32_16x16x32_bf16(ql[i][ks], kfh[j], sc[i][j], 0, 0, 0);
          }
      }

#pragma unroll
      for (int i = 0; i < 2; ++i) {
#pragma unroll
        for (int r = 0; r < 4; ++r) {
          const int qg = qt * 128 + w * 32 + i * 16 + quad * 4 + r;
          float mx = -1e30f;
#pragma unroll
          for (int j = 0; j < 4; ++j) {
            float v = sc[i][j][r] * 0.125f;
            const int kg = kt * 64 + j * 16 + m16;
            if (kg > qg) v = -1e30f;
            sc[i][j][r] = v;
            mx = fmaxf(mx, v);
          }
#pragma unroll
          for (int m = 1; m < 16; m <<= 1) mx = fmaxf(mx, __shfl_xor(mx, m));
          const float mnew = fmaxf(mr[i][r], mx);
          const float alpha = __expf(mr[i][r] - mnew);
          mr[i][r] = mnew;
          float ls = 0.f;
#pragma unroll
          for (int j = 0; j < 4; ++j) {
            const float pv = __expf(sc[i][j][r] - mnew);
            sc[i][j][r] = pv;
            ls += pv;
          }
#pragma unroll
          for (int m = 1; m < 16; m <<= 1) ls += __shfl_xor(ls, m);
          lr[i][r] = lr[i][r] * alpha + ls;
#pragma unroll
          for (int n = 0; n < 4; ++n) o[i][n][r] *= alpha;
        }
#pragma unroll
        for (int j = 0; j < 4; ++j)
#pragma unroll
          for (int r = 0; r < 4; ++r)
            P[w][(i * 16 + quad * 4 + r) * 72 + j * 16 + m16] = f2bf(sc[i][j][r]);
      }
      __syncthreads();

#pragma unroll
      for (int ks2 = 0; ks2 < 2; ++ks2) {
        bf16x8 pf[2], vf[4];
#pragma unroll
        for (int i = 0; i < 2; ++i)
          pf[i] = *(const bf16x8*)(&P[w][(i * 16 + m16) * 72 + ks2 * 32 + quad * 8]);
        const int cg = ks2 * 4 + quad;
#pragma unroll
        for (int n = 0; n < 4; ++n) {
          const int rV = n * 16 + m16;
          vf[n] = *(const bf16x8*)(Vs + rV * 64 + ((cg ^ (rV & 7)) * 8));
        }
#pragma unroll
        for (int i = 0; i < 2; ++i)
#pragma unroll
          for (int n = 0; n < 4; ++n)
            o[i][n] = __builtin_amdgcn_mfma_f32_16x16x32_bf16(pf[i], vf[n], o[i][n], 0, 0, 0);
      }
      __syncthreads();
    }

#pragma unroll
    for (int i = 0; i < 2; ++i)
#pragma unroll
      for (int r = 0; r < 4; ++r) {
        const float inv = 1.f / lr[i][r];
        const size_t row = (size_t)(b * 2048 + qt * 128 + w * 32 + i * 16 + quad * 4 + r);
#pragma unroll
        for (int n = 0; n < 4; ++n)
          Hout[row * 1024 + h * 64 + n * 16 + m16] = f2bf(o[i][n][r] * inv);
      }
  }
}

// --------------------------------- swiglu ----------------------------------

__global__ __launch_bounds__(256) void swiglu_k(uint16_t* __restrict__ a,
                                                const uint16_t* __restrict__ g, int n8) {
  const int t = blockIdx.x * 256 + threadIdx.x;
  if (t >= n8) return;
  union { uint4 v; uint16_t u[8]; } av, gv, hv;
  av.v = ((const uint4*)a)[t];
  gv.v = ((const uint4*)g)[t];
#pragma unroll
  for (int e = 0; e < 8; ++e) {
    const float x = bf2f(av.u[e]);
    const float gg = bf2f(gv.u[e]);
    const float sw = x / (1.f + __expf(-x));
    hv.u[e] = f2bf(sw * gg);
  }
  ((uint4*)a)[t] = hv.v;
}

// ------------------------------ orchestration -------------------------------

extern "C" void kernel_launch(void* const* d_in, const int* in_sizes, int n_in,
                              void* d_out, int out_size, void* d_ws, size_t ws_size,
                              hipStream_t stream) {
  (void)in_sizes; (void)n_in; (void)out_size; (void)ws_size;
  const float* x   = (const float*)d_in[0];
  const int*   pos = (const int*)  d_in[1];
  const float* q_w = (const float*)d_in[2];
  const float* k_w = (const float*)d_in[3];
  const float* v_w = (const float*)d_in[4];
  const float* o_w = (const float*)d_in[5];
  const float* g1  = (const float*)d_in[6];
  const float* g2  = (const float*)d_in[7];
  const float* w1  = (const float*)d_in[8];
  const float* w2  = (const float*)d_in[9];
  const float* w3  = (const float*)d_in[10];

  char* ws = (char*)d_ws;
  uint16_t* wqk_hi = (uint16_t*)(ws + 0);
  uint16_t* wqk_lo = (uint16_t*)(ws + 4194304);
  uint16_t* wv     = (uint16_t*)(ws + 8388608);
  uint16_t* wo     = (uint16_t*)(ws + 10485760);
  uint16_t* w1b    = (uint16_t*)(ws + 12582912);
  uint16_t* w3b    = (uint16_t*)(ws + 20971520);
  uint16_t* w2b    = (uint16_t*)(ws + 29360128);
  uint16_t* xn_hi  = (uint16_t*)(ws + 37748736);
  uint16_t* xn_lo  = (uint16_t*)(ws + 54525952);
  uint16_t* vbuf   = (uint16_t*)(ws + 71303168);
  uint16_t* vt     = (uint16_t*)(ws + 88080384);
  uint16_t* qk_hi  = (uint16_t*)(ws + 104857600);
  uint16_t* qk_lo  = (uint16_t*)(ws + 138412032);
  uint16_t* hbuf   = (uint16_t*)(ws + 171966464);
  float*    ores   = (float*)   (ws + 188743680);
  uint16_t* on2    = (uint16_t*)(ws + 222298112);
  // overlays (regions dead by the time these are written):
  uint16_t* abuf   = (uint16_t*)(ws + 104857600);  // over qk_hi+qk_lo (67.1 MB)
  uint16_t* gbuf   = (uint16_t*)(ws + 37748736);   // over xn_hi..vt   (67.1 MB)
  // total ws required: 239,075,328 bytes

  cvt_split_qk_k<<<2048, 256, 0, stream>>>(q_w, k_w, wqk_hi, wqk_lo);
  cvt_bf16_k<<<1024, 256, 0, stream>>>(v_w, wv, 262144);
  cvt_bf16_k<<<1024, 256, 0, stream>>>(o_w, wo, 262144);
  cvt_bf16_k<<<4096, 256, 0, stream>>>(w1, w1b, 1048576);
  cvt_bf16_k<<<4096, 256, 0, stream>>>(w3, w3b, 1048576);
  cvt_bf16_k<<<4096, 256, 0, stream>>>(w2, w2b, 1048576);

  rmsnorm_k<true><<<8192, 256, 0, stream>>>(x, g1, xn_hi, xn_lo);

  gemm_bt_split_k<<<dim3(16, 64), 256, 0, stream>>>(xn_hi, xn_lo, wqk_hi, wqk_lo,
                                                    qk_hi, qk_lo, 2048, 1024);
  gemm_bt_k<0><<<dim3(8, 64), 256, 0, stream>>>(xn_hi, wv, (void*)vbuf, nullptr, 1024, 1024);

  rope_k<<<32768, 256, 0, stream>>>(qk_hi, qk_lo, pos);
  transpose_v_k<<<dim3(32, 64), 256, 0, stream>>>(vbuf, vt);

  flash_k<<<dim3(8, 64), 256, 0, stream>>>(qk_hi, qk_lo, vt, hbuf);

  gemm_bt_k<1><<<dim3(8, 64), 256, 0, stream>>>(hbuf, wo, (void*)ores, x, 1024, 1024);

  rmsnorm_k<false><<<8192, 256, 0, stream>>>(ores, g2, on2, nullptr);

  gemm_bt_k<0><<<dim3(32, 64), 256, 0, stream>>>(on2, w1b, (void*)abuf, nullptr, 4096, 1024);
  gemm_bt_k<0><<<dim3(32, 64), 256, 0, stream>>>(on2, w3b, (void*)gbuf, nullptr, 4096, 1024);
  swiglu_k<<<16384, 256, 0, stream>>>(abuf, gbuf, 4194304);

  gemm_bt_k<1><<<dim3(8, 64), 256, 0, stream>>>(abuf, w2b, d_out, ores, 1024, 4096);
}